// Round 9
// baseline (373.238 us; speedup 1.0000x reference)
//
#include <hip/hip_runtime.h>
#include <hip/hip_bf16.h>

#define B_ 4
#define N_ 4096
#define D_ 1024
#define H_ 16

typedef __attribute__((ext_vector_type(4))) float f32x4;
typedef __attribute__((ext_vector_type(8))) short s16x8;
typedef __attribute__((ext_vector_type(4))) unsigned int u32x4;

__device__ __forceinline__ ushort f2bf(float f) {
  union { float f; unsigned u; } v; v.f = f;
  unsigned u = v.u;
  return (ushort)((u + 0x7fffu + ((u >> 16) & 1u)) >> 16);
}

__device__ __forceinline__ void gld16(const ushort* g, ushort* lds_base) {
  __builtin_amdgcn_global_load_lds(
      (const __attribute__((address_space(1))) unsigned int*)g,
      (__attribute__((address_space(3))) unsigned int*)lds_base, 16, 0, 0);
}

__device__ __forceinline__ unsigned cvtpk(float lo, float hi) {
  unsigned r;
  asm("v_cvt_pk_bf16_f32 %0, %1, %2" : "=v"(r) : "v"(lo), "v"(hi));
  return r;
}

#define WAITVM(N) asm volatile("s_waitcnt vmcnt(" #N ")" ::: "memory")
#define LGKM0 asm volatile("s_waitcnt lgkmcnt(0)" ::: "memory")
#define SBAR __builtin_amdgcn_sched_barrier(0)
#define BARRIER __builtin_amdgcn_s_barrier()

// ---------------- weight convert ----------------
__global__ void conv_w_kernel(const float* __restrict__ w0, const float* __restrict__ w1,
                              const float* __restrict__ w2, const float* __restrict__ w3,
                              ushort* __restrict__ dst) {
  const int z = blockIdx.z;
  const float* src = z == 0 ? w0 : z == 1 ? w1 : z == 2 ? w2 : w3;
  ushort* d = dst + (long)z * (D_ * D_);
  const long i0 = ((long)blockIdx.x * 256 + threadIdx.x) * 8;
  const long STR = (long)128 * 256 * 8;
#pragma unroll
  for (int u = 0; u < 4; ++u) {
    f32x4 a = *(const f32x4*)(src + i0 + u * STR);
    f32x4 b = *(const f32x4*)(src + i0 + u * STR + 4);
    s16x8 o;
    o[0] = (short)f2bf(a[0]); o[1] = (short)f2bf(a[1]); o[2] = (short)f2bf(a[2]); o[3] = (short)f2bf(a[3]);
    o[4] = (short)f2bf(b[0]); o[5] = (short)f2bf(b[1]); o[6] = (short)f2bf(b[2]); o[7] = (short)f2bf(b[3]);
    *(s16x8*)(d + i0 + u * STR) = o;
  }
}

// ---------------- gemm body: C[m,n] = sum_k A[m,k]*B[n,k], K=1024 ----------------
// 128x128 tile, BK=64, 256 threads = 4 waves (2M x 2N), per-wave out 64x64 (acc 4x4).
// T3-minimal schedule: stage(t+1) BEFORE MFMA(t); counted WAITVM(8) leaves A-reg
// loads in flight; one raw barrier/step; double-buffered 64KB LDS.
// Swizzle (verified r8, conflicts=0): LDS[row][dslot] = global col (dslot^(row&7)).
// EPI: 0 = bf16 store (V), 1 = +bias head-softmax *1/8 (Q), 2 = exp + col partials (K),
//      3 = +bias fp32 store (final). Pointers pre-offset by wrapper.
template <int EPI, bool AFP32>
__device__ __forceinline__ void gemm_body(
    const void* __restrict__ Av, const ushort* __restrict__ Bm,
    void* __restrict__ Cv, const float* __restrict__ bias, float* __restrict__ kpart,
    int m0, int n0) {
  __shared__ ushort As[16384];  // 2 bufs x [128 rows][64 cols]
  __shared__ ushort Bs[16384];
  const int N = 1024;
  const int tid = threadIdx.x;
  const int lane = tid & 63, wave = tid >> 6;
  const int fl = lane & 15, fh = lane >> 4;
  const int wm = wave >> 1, wn = wave & 1;
  f32x4 acc[4][4] = {};

  // gld16 map: chunk c = tid + i*256 -> row = (tid>>3)+32i, dest slot = tid&7.
  // Source col pre-swizzled: scol = ((tid&7) ^ ((tid>>3)&7)) * 8  (row&7 == (tid>>3)&7).
  const int r0 = tid >> 3;
  const int scol = ((tid & 7) ^ (r0 & 7)) * 8;
  const ushort* Bsrc = Bm + (long)(n0 + r0) * 1024 + scol;
  const ushort* Ab = (const ushort*)Av;
  const ushort* Asrc = AFP32 ? nullptr : (Ab + (long)(m0 + r0) * 1024 + scol);

  // A fp32 reg staging: row ar = tid>>1, 32 cols at ch*32; swizzled ds_write_b128 x4.
  const int ar = tid >> 1, ch = tid & 1;
  const float* apA = AFP32 ? ((const float*)Av + (long)(m0 + ar) * 1024 + ch * 32) : nullptr;
  int awo[4];
#pragma unroll
  for (int w = 0; w < 4; ++w) awo[w] = ar * 64 + (((ch * 4 + w) ^ (ar & 7)) * 8);

  f32x4 pa0, pa1, pa2, pa3, pa4, pa5, pa6, pa7;
  f32x4 pb0, pb1, pb2, pb3, pb4, pb5, pb6, pb7;

#define GLD_B(T, CUR) do { \
    _Pragma("unroll") for (int i = 0; i < 4; ++i) \
      gld16(Bsrc + (T) * 64 + i * 32768, Bs + (CUR) * 8192 + tid * 8 + i * 2048); } while (0)
#define GLD_A(T, CUR) do { \
    _Pragma("unroll") for (int i = 0; i < 4; ++i) \
      gld16(Asrc + (T) * 64 + i * 32768, As + (CUR) * 8192 + tid * 8 + i * 2048); } while (0)
#define PLOAD(T, S) do { \
    S##0 = *(const f32x4*)(apA + (T) * 64);      S##1 = *(const f32x4*)(apA + (T) * 64 + 4); \
    S##2 = *(const f32x4*)(apA + (T) * 64 + 8);  S##3 = *(const f32x4*)(apA + (T) * 64 + 12); \
    S##4 = *(const f32x4*)(apA + (T) * 64 + 16); S##5 = *(const f32x4*)(apA + (T) * 64 + 20); \
    S##6 = *(const f32x4*)(apA + (T) * 64 + 24); S##7 = *(const f32x4*)(apA + (T) * 64 + 28); } while (0)
#define CVT_WRITE(S, CUR) do { \
    u32x4 _w; \
    _w[0] = cvtpk(S##0[0], S##0[1]); _w[1] = cvtpk(S##0[2], S##0[3]); \
    _w[2] = cvtpk(S##1[0], S##1[1]); _w[3] = cvtpk(S##1[2], S##1[3]); \
    *(u32x4*)(As + (CUR) * 8192 + awo[0]) = _w; \
    _w[0] = cvtpk(S##2[0], S##2[1]); _w[1] = cvtpk(S##2[2], S##2[3]); \
    _w[2] = cvtpk(S##3[0], S##3[1]); _w[3] = cvtpk(S##3[2], S##3[3]); \
    *(u32x4*)(As + (CUR) * 8192 + awo[1]) = _w; \
    _w[0] = cvtpk(S##4[0], S##4[1]); _w[1] = cvtpk(S##4[2], S##4[3]); \
    _w[2] = cvtpk(S##5[0], S##5[1]); _w[3] = cvtpk(S##5[2], S##5[3]); \
    *(u32x4*)(As + (CUR) * 8192 + awo[2]) = _w; \
    _w[0] = cvtpk(S##6[0], S##6[1]); _w[1] = cvtpk(S##6[2], S##6[3]); \
    _w[2] = cvtpk(S##7[0], S##7[1]); _w[3] = cvtpk(S##7[2], S##7[3]); \
    *(u32x4*)(As + (CUR) * 8192 + awo[3]) = _w; } while (0)
#define MFMA_STEP(CUR) do { \
    _Pragma("unroll") for (int h2 = 0; h2 < 2; ++h2) { \
      s16x8 fb[4]; \
      _Pragma("unroll") for (int j = 0; j < 4; ++j) \
        fb[j] = *(const s16x8*)(Bs + (CUR) * 8192 + (wn * 64 + j * 16 + fl) * 64 + \
                                (((h2 * 4 + fh) ^ (fl & 7)) * 8)); \
      _Pragma("unroll") for (int i = 0; i < 4; ++i) { \
        s16x8 fa = *(const s16x8*)(As + (CUR) * 8192 + (wm * 64 + i * 16 + fl) * 64 + \
                                   (((h2 * 4 + fh) ^ (fl & 7)) * 8)); \
        _Pragma("unroll") for (int j = 0; j < 4; ++j) \
          acc[i][j] = __builtin_amdgcn_mfma_f32_16x16x32_bf16(fa, fb[j], acc[i][j], 0, 0, 0); \
      } } } while (0)

  if constexpr (AFP32) {
    // prologue: tile0 -> buf0 (reg path), B0 -> buf0; tile1 regs in flight
    PLOAD(0, pa);
    CVT_WRITE(pa, 0);          // compiler-inserted vmcnt drains pa
    GLD_B(0, 0);               // 4 gld16
    PLOAD(1, pb);              // 8 reg loads stay in flight
    WAITVM(8); LGKM0; BARRIER; SBAR;
#pragma unroll 1
    for (int t = 0; t < 14; t += 2) {
      // step t (cur=0): stage tile t+1 -> buf1, prefetch regs tile t+2
      CVT_WRITE(pb, 1);
      GLD_B(t + 1, 1);
      PLOAD(t + 2, pa);
      MFMA_STEP(0);
      WAITVM(8); LGKM0; BARRIER; SBAR;
      // step t+1 (cur=1)
      CVT_WRITE(pa, 0);
      GLD_B(t + 2, 0);
      PLOAD(t + 3, pb);
      MFMA_STEP(1);
      WAITVM(8); LGKM0; BARRIER; SBAR;
    }
    // step 14 (cur=0): stage tile15 -> buf1
    CVT_WRITE(pb, 1);
    GLD_B(15, 1);
    MFMA_STEP(0);
    WAITVM(0); LGKM0; BARRIER; SBAR;
    // step 15 (cur=1)
    MFMA_STEP(1);
  } else {
    GLD_A(0, 0); GLD_B(0, 0);
    WAITVM(0); BARRIER; SBAR;
#pragma unroll 1
    for (int t = 0; t < 15; ++t) {
      GLD_A(t + 1, (t + 1) & 1);
      GLD_B(t + 1, (t + 1) & 1);
      MFMA_STEP(t & 1);
      WAITVM(0); BARRIER; SBAR;
    }
    MFMA_STEP(1);
  }
#undef GLD_B
#undef GLD_A
#undef PLOAD
#undef CVT_WRITE
#undef MFMA_STEP

  // ---- epilogues: rows m0 + wm*64 + i*16 + fh*4 + r, cols n0 + wn*64 + j*16 + fl
  if constexpr (EPI == 0) {
    ushort* C = (ushort*)Cv;
#pragma unroll
    for (int j = 0; j < 4; ++j) {
      int col = n0 + wn * 64 + j * 16 + fl;
#pragma unroll
      for (int i = 0; i < 4; ++i)
#pragma unroll
        for (int r = 0; r < 4; ++r) {
          int row = m0 + wm * 64 + i * 16 + fh * 4 + r;
          C[(long)row * N + col] = f2bf(acc[i][j][r]);
        }
    }
  } else if constexpr (EPI == 1) {
    ushort* C = (ushort*)Cv;
    float bcol[4];
#pragma unroll
    for (int j = 0; j < 4; ++j) bcol[j] = bias[n0 + wn * 64 + j * 16 + fl];
#pragma unroll
    for (int i = 0; i < 4; ++i)
#pragma unroll
      for (int r = 0; r < 4; ++r) {
        float v[4];
#pragma unroll
        for (int j = 0; j < 4; ++j) v[j] = acc[i][j][r] + bcol[j];
        float m = fmaxf(fmaxf(v[0], v[1]), fmaxf(v[2], v[3]));
#pragma unroll
        for (int o = 1; o <= 8; o <<= 1) m = fmaxf(m, __shfl_xor(m, o));
        float e[4], s = 0.f;
#pragma unroll
        for (int j = 0; j < 4; ++j) { e[j] = __expf(v[j] - m); s += e[j]; }
#pragma unroll
        for (int o = 1; o <= 8; o <<= 1) s += __shfl_xor(s, o);
        float sc = 0.125f / s;
        int row = m0 + wm * 64 + i * 16 + fh * 4 + r;
#pragma unroll
        for (int j = 0; j < 4; ++j)
          C[(long)row * N + n0 + wn * 64 + j * 16 + fl] = f2bf(e[j] * sc);
      }
  } else if constexpr (EPI == 2) {
    ushort* C = (ushort*)Cv;
    float csum[4] = {};
#pragma unroll
    for (int j = 0; j < 4; ++j) {
      int col = n0 + wn * 64 + j * 16 + fl;
#pragma unroll
      for (int i = 0; i < 4; ++i)
#pragma unroll
        for (int r = 0; r < 4; ++r) {
          int row = m0 + wm * 64 + i * 16 + fh * 4 + r;
          float e = __expf(acc[i][j][r]);
          csum[j] += e;
          C[(long)row * N + col] = f2bf(e);
        }
    }
#pragma unroll
    for (int j = 0; j < 4; ++j) {
#pragma unroll
      for (int o = 16; o <= 32; o <<= 1) csum[j] += __shfl_xor(csum[j], o);
    }
    if (fh == 0) {
      int b = m0 >> 12;
      int chunk = ((m0 & 4095) >> 7) * 2 + wm;  // 64 chunks of 64 rows per batch
#pragma unroll
      for (int j = 0; j < 4; ++j)
        kpart[(long)b * 65536 + (long)chunk * 1024 + n0 + wn * 64 + j * 16 + fl] = csum[j];
    }
  } else {
    float* C = (float*)Cv;
#pragma unroll
    for (int j = 0; j < 4; ++j) {
      int col = n0 + wn * 64 + j * 16 + fl;
      float bv = bias[col];
#pragma unroll
      for (int i = 0; i < 4; ++i)
#pragma unroll
        for (int r = 0; r < 4; ++r) {
          int row = m0 + wm * 64 + i * 16 + fh * 4 + r;
          C[(long)row * N + col] = acc[i][j][r] + bv;
        }
    }
  }
}

// ---------------- named GEMM kernels ----------------
__global__ __launch_bounds__(256, 2) void gemm_q(const float* __restrict__ A,
                                                 const ushort* __restrict__ Bm,
                                                 ushort* __restrict__ C,
                                                 const float* __restrict__ bias) {
  gemm_body<1, true>(A, Bm, C, bias, nullptr, blockIdx.x * 128, blockIdx.y * 128);
}
__global__ __launch_bounds__(256, 2) void gemm_k(const float* __restrict__ A,
                                                 const ushort* __restrict__ Bm,
                                                 ushort* __restrict__ C,
                                                 float* __restrict__ kpart) {
  gemm_body<2, true>(A, Bm, C, nullptr, kpart, blockIdx.x * 128, blockIdx.y * 128);
}
__global__ __launch_bounds__(256, 2) void gemm_v(const float* __restrict__ A,
                                                 const ushort* __restrict__ Bm,
                                                 ushort* __restrict__ C) {
  gemm_body<0, true>(A, Bm, C, nullptr, nullptr, blockIdx.x * 128, blockIdx.y * 128);
}
__global__ __launch_bounds__(256, 2) void gemm_o(const ushort* __restrict__ A,
                                                 const ushort* __restrict__ Bm,
                                                 float* __restrict__ C,
                                                 const float* __restrict__ bias) {
  const int z = blockIdx.z;
  gemm_body<3, false>(A + (long)z * 4096 * 1024, Bm + (long)z * 1024 * 1024,
                      C + (long)z * 4096 * 1024, bias, nullptr,
                      blockIdx.x * 128, blockIdx.y * 128);
}

// ---------------- colinv[b][d] = 1 / sum_c kpart[b][c][d] ----------------
__global__ void ksm2_kernel(const float* __restrict__ kpart, float* __restrict__ colinv) {
  int idx = blockIdx.x * 256 + threadIdx.x;  // b*1024+d
  int b = idx >> 10, d = idx & 1023;
  float s = 0.f;
  for (int c = 0; c < 64; ++c) s += kpart[(long)b * 65536 + (long)c * 1024 + d];
  colinv[idx] = 1.0f / s;
}

// ---------------- ctx partial: part[chunk][bh][dk][e] = sum_{n in chunk(512)} expk[n,dk]*v[n,e] ----------------
__global__ __launch_bounds__(256, 2) void ctx_partial_kernel(
    const ushort* __restrict__ Ksm, const ushort* __restrict__ Vp, float* __restrict__ part) {
  __shared__ ushort Ks[128 * 64];
  __shared__ ushort Vs[128 * 64];
  const int chunk = blockIdx.x;  // 8 chunks of 512 rows
  const int bh = blockIdx.y;     // 64
  const int b = bh >> 4, h = bh & 15;
  const int tid = threadIdx.x, wave = tid >> 6, lane = tid & 63;
  const int fl = lane & 15, fh = lane >> 4;
  f32x4 acc[4] = {};
  for (int t = 0; t < 4; ++t) {
    const long base = ((long)(b * N_ + chunk * 512 + t * 128)) * D_ + h * 64;
    __syncthreads();
#pragma unroll
    for (int i = 0; i < 4; ++i) {
      int c = i * 256 + tid;
      int r = c >> 3, k8 = (c & 7) * 8;
      ushort* lk = Ks + (long)(i * 256 + wave * 64) * 8;
      ushort* lv = Vs + (long)(i * 256 + wave * 64) * 8;
      gld16(Ksm + base + (long)r * D_ + k8, lk);
      gld16(Vp + base + (long)r * D_ + k8, lv);
    }
    __syncthreads();
#pragma unroll
    for (int s = 0; s < 4; ++s) {
      s16x8 fa;
#pragma unroll
      for (int j = 0; j < 8; ++j)
        fa[j] = (short)Ks[(s * 32 + fh * 8 + j) * 64 + wave * 16 + fl];
#pragma unroll
      for (int jt = 0; jt < 4; ++jt) {
        s16x8 fb;
#pragma unroll
        for (int j = 0; j < 8; ++j)
          fb[j] = (short)Vs[(s * 32 + fh * 8 + j) * 64 + jt * 16 + fl];
        acc[jt] = __builtin_amdgcn_mfma_f32_16x16x32_bf16(fa, fb, acc[jt], 0, 0, 0);
      }
    }
  }
  float* dst = part + ((long)chunk * 64 + bh) * 4096;
#pragma unroll
  for (int jt = 0; jt < 4; ++jt)
#pragma unroll
    for (int r = 0; r < 4; ++r)
      dst[(wave * 16 + fh * 4 + r) * 64 + jt * 16 + fl] = acc[jt][r];
}

// ctxb[bh][dk][e] = bf16( colinv[b,h*64+dk] * sum_ch part + bv[h*64+e] )
__global__ void ctx_reduce_kernel(const float* __restrict__ part, const float* __restrict__ bv,
                                  const float* __restrict__ colinv, ushort* __restrict__ ctxb) {
  int idx = blockIdx.x * 256 + threadIdx.x;
  int e = idx & 63;
  int dk = (idx >> 6) & 63;
  int h = (idx >> 12) & 15;
  int b = idx >> 16;
  float s = 0.f;
#pragma unroll
  for (int c = 0; c < 8; ++c) s += part[(long)c * 262144 + idx];
  ctxb[idx] = f2bf(s * colinv[b * 1024 + h * 64 + dk] + bv[h * 64 + e]);
}

// Mb[b][o, h*64+dk] = sum_e Wo[o, h*64+e] * ctx[b,h][dk,e]
__global__ __launch_bounds__(256, 2) void mb_kernel(
    const ushort* __restrict__ Wob, const ushort* __restrict__ ctxb, ushort* __restrict__ Mb) {
  const int o0 = blockIdx.x * 64, h = blockIdx.y, b = blockIdx.z;
  const int tid = threadIdx.x, wave = tid >> 6, lane = tid & 63;
  const int fl = lane & 15, fh = lane >> 4;
  const ushort* ctxh = ctxb + ((long)(b * 16 + h)) * 4096;
  f32x4 acc[4] = {};
#pragma unroll
  for (int s = 0; s < 2; ++s) {
    s16x8 fa = *(const s16x8*)(Wob + (long)(o0 + wave * 16 + fl) * D_ + h * 64 + s * 32 + fh * 8);
#pragma unroll
    for (int jt = 0; jt < 4; ++jt) {
      s16x8 fb = *(const s16x8*)(ctxh + (long)(jt * 16 + fl) * 64 + s * 32 + fh * 8);
      acc[jt] = __builtin_amdgcn_mfma_f32_16x16x32_bf16(fa, fb, acc[jt], 0, 0, 0);
    }
  }
  ushort* dst = Mb + (long)b * (D_ * D_);
#pragma unroll
  for (int jt = 0; jt < 4; ++jt)
#pragma unroll
    for (int r = 0; r < 4; ++r)
      dst[(long)(o0 + wave * 16 + fh * 4 + r) * D_ + h * 64 + jt * 16 + fl] = f2bf(acc[jt][r]);
}

// ---------------- launch ----------------
extern "C" void kernel_launch(void* const* d_in, const int* in_sizes, int n_in,
                              void* d_out, int out_size, void* d_ws, size_t ws_size,
                              hipStream_t stream) {
  const float* q_in = (const float*)d_in[0];
  const float* k_in = (const float*)d_in[1];
  const float* v_in = (const float*)d_in[2];
  const float* Wq = (const float*)d_in[3];
  const float* bq = (const float*)d_in[4];
  const float* Wk = (const float*)d_in[5];
  const float* Wv = (const float*)d_in[7];
  const float* bv = (const float*)d_in[8];
  const float* Wo = (const float*)d_in[9];
  const float* bo = (const float*)d_in[10];

  char* ws = (char*)d_ws;
  ushort* Wb = (ushort*)(ws + 0);              // 8 MB
  ushort* Qp = (ushort*)(ws + 8388608);        // 32 MB
  ushort* Kp = (ushort*)(ws + 41943040);       // 32 MB
  ushort* Vp = (ushort*)(ws + 75497472);       // 32 MB
  float* kpart = (float*)(ws + 109051904);     // [4][64][1024] f32 = 1 MB
  float* colinv = (float*)(ws + 110100480);    // 16 KB
  float* ctxpart = (float*)(ws + 110116864);   // [8][64][4096] f32 = 8 MB
  ushort* ctxb = (ushort*)(ws + 118505472);    // 512 KB
  ushort* Mb = (ushort*)(ws + 119029760);      // 8 MB

  ushort* Wbq = Wb;
  ushort* Wbk = Wb + 1048576;
  ushort* Wbv = Wb + 2097152;
  ushort* Wbo = Wb + 3145728;

  conv_w_kernel<<<dim3(128, 1, 4), 256, 0, stream>>>(Wq, Wk, Wv, Wo, Wb);

  // projections: fp32 A read directly; M=16384 (128 m-tiles), N=1024 (8 n-tiles)
  gemm_q<<<dim3(128, 8), 256, 0, stream>>>(q_in, Wbq, Qp, bq);
  gemm_k<<<dim3(128, 8), 256, 0, stream>>>(k_in, Wbk, Kp, kpart);
  gemm_v<<<dim3(128, 8), 256, 0, stream>>>(v_in, Wbv, Vp);

  ksm2_kernel<<<16, 256, 0, stream>>>(kpart, colinv);

  ctx_partial_kernel<<<dim3(8, 64), 256, 0, stream>>>(Kp, Vp, ctxpart);
  ctx_reduce_kernel<<<1024, 256, 0, stream>>>(ctxpart, bv, colinv, ctxb);
  mb_kernel<<<dim3(16, 16, 4), 256, 0, stream>>>(Wbo, ctxb, Mb);

  // final: per-batch out = Qp_b @ Mb_b^T + bo (fp32 out); 32 m-tiles x 8 n-tiles x 4 z
  gemm_o<<<dim3(32, 8, 4), 256, 0, stream>>>(Qp, Mb, (float*)d_out, bo);
}

// Round 10
// 313.439 us; speedup vs baseline: 1.1908x; 1.1908x over previous
//
#include <hip/hip_runtime.h>
#include <hip/hip_bf16.h>

#define B_ 4
#define N_ 4096
#define D_ 1024
#define H_ 16

typedef __attribute__((ext_vector_type(4))) float f32x4;
typedef __attribute__((ext_vector_type(8))) short s16x8;
typedef __attribute__((ext_vector_type(4))) unsigned int u32x4;

__device__ __forceinline__ ushort f2bf(float f) {
  union { float f; unsigned u; } v; v.f = f;
  unsigned u = v.u;
  return (ushort)((u + 0x7fffu + ((u >> 16) & 1u)) >> 16);
}

__device__ __forceinline__ void gld16(const ushort* g, ushort* lds_base) {
  __builtin_amdgcn_global_load_lds(
      (const __attribute__((address_space(1))) unsigned int*)g,
      (__attribute__((address_space(3))) unsigned int*)lds_base, 16, 0, 0);
}

__device__ __forceinline__ unsigned cvtpk(float lo, float hi) {
  unsigned r;
  asm("v_cvt_pk_bf16_f32 %0, %1, %2" : "=v"(r) : "v"(lo), "v"(hi));
  return r;
}

#define WAITVM(N) asm volatile("s_waitcnt vmcnt(" #N ")" ::: "memory")
#define LGKM0 asm volatile("s_waitcnt lgkmcnt(0)" ::: "memory")
#define SBAR __builtin_amdgcn_sched_barrier(0)
#define BARRIER __builtin_amdgcn_s_barrier()

// ---------------- weight convert ----------------
__global__ void conv_w_kernel(const float* __restrict__ w0, const float* __restrict__ w1,
                              const float* __restrict__ w2, const float* __restrict__ w3,
                              ushort* __restrict__ dst) {
  const int z = blockIdx.z;
  const float* src = z == 0 ? w0 : z == 1 ? w1 : z == 2 ? w2 : w3;
  ushort* d = dst + (long)z * (D_ * D_);
  const long i0 = ((long)blockIdx.x * 256 + threadIdx.x) * 8;
  const long STR = (long)128 * 256 * 8;
#pragma unroll
  for (int u = 0; u < 4; ++u) {
    f32x4 a = *(const f32x4*)(src + i0 + u * STR);
    f32x4 b = *(const f32x4*)(src + i0 + u * STR + 4);
    s16x8 o;
    o[0] = (short)f2bf(a[0]); o[1] = (short)f2bf(a[1]); o[2] = (short)f2bf(a[2]); o[3] = (short)f2bf(a[3]);
    o[4] = (short)f2bf(b[0]); o[5] = (short)f2bf(b[1]); o[6] = (short)f2bf(b[2]); o[7] = (short)f2bf(b[3]);
    *(s16x8*)(d + i0 + u * STR) = o;
  }
}

// ---------------- gemm body: C[m,n] = sum_k A[m,k]*B[n,k], K=1024 ----------------
// r5 geometry: 128x128 tile, BK=32, 256 thr = 4 waves (2Mx2N), acc 4x4/wave.
// Minimal 2-phase (guide T3): stage(t+1,buf^1) -> MFMA(t,buf) -> counted WAITVM
// (A-reg prefetch stays in flight across the barrier) -> 1 raw barrier/step.
// Double buffer 2 x 16KB = 32 KB LDS. Swizzle (r8-verified, 0 conflicts):
// LDS[row][slot] holds global col slot^((row>>1)&3); reads XOR the same.
// EPI: 0 = bf16 store (V), 1 = +bias head-softmax *1/8 (Q), 2 = exp + col partials (K),
//      3 = +bias fp32 store (final). Pointers pre-offset by wrapper.
template <int EPI, bool AFP32>
__device__ __forceinline__ void gemm_body(
    const void* __restrict__ Av, const ushort* __restrict__ Bm,
    void* __restrict__ Cv, const float* __restrict__ bias, float* __restrict__ kpart,
    int m0, int n0) {
  __shared__ ushort As[8192];  // 2 bufs x [128][32]
  __shared__ ushort Bs[8192];
  const int N = 1024;
  const int tid = threadIdx.x;
  const int lane = tid & 63, wave = tid >> 6;
  const int fl = lane & 15, fh = lane >> 4;
  const int wm = wave >> 1, wn = wave & 1;
  f32x4 acc[4][4] = {};

  // staging: 2 chunks/thread/tensor/step: c0 = tid (rows 0-63), c1 = tid+256 (rows 64-127)
  // row = c>>2, slot = c&3; source col inverse-swizzled (slot ^ ((row>>1)&3)); dest linear.
  const int r0 = tid >> 2;                       // 0..63 ; second chunk row = r0+64
  const int s8 = (((tid & 3) ^ ((r0 >> 1) & 3)) * 8);  // same XOR for r0+64
  const ushort* Bsrc0 = Bm + (long)(n0 + r0) * 1024 + s8;
  const ushort* Bsrc1 = Bm + (long)(n0 + r0 + 64) * 1024 + s8;
  const ushort* Ab = (const ushort*)Av;
  const ushort* Asrc0 = AFP32 ? nullptr : (Ab + (long)(m0 + r0) * 1024 + s8);
  const ushort* Asrc1 = AFP32 ? nullptr : (Ab + (long)(m0 + r0 + 64) * 1024 + s8);

  // fp32-A reg staging: row ar = tid>>1 (0..127), 16 floats at ch*16 = 4 dwordx4 loads;
  // two swizzled ds_write_b128 at slots ch*2, ch*2+1.
  const int ar = tid >> 1, ch = tid & 1;
  const float* apA = AFP32 ? ((const float*)Av + (long)(m0 + ar) * 1024 + ch * 16) : nullptr;
  const int aw0 = ar * 32 + (((ch * 2) ^ ((ar >> 1) & 3)) * 8);
  const int aw1 = ar * 32 + (((ch * 2 + 1) ^ ((ar >> 1) & 3)) * 8);

  // swizzled fragment-read: row = base16 + fl -> (row>>1)&3 == (fl>>1)&3
  const int fro = (fh ^ ((fl >> 1) & 3)) * 8;

  f32x4 qa0, qa1, qa2, qa3, qb0, qb1, qb2, qb3;

#define ISSUE_B(T, CUR) do { \
    gld16(Bsrc0 + (T) * 32, Bs + (CUR) * 4096 + tid * 8); \
    gld16(Bsrc1 + (T) * 32, Bs + (CUR) * 4096 + 2048 + tid * 8); } while (0)
#define ISSUE_A16(T, CUR) do { \
    gld16(Asrc0 + (T) * 32, As + (CUR) * 4096 + tid * 8); \
    gld16(Asrc1 + (T) * 32, As + (CUR) * 4096 + 2048 + tid * 8); } while (0)
#define ISSUE_P(T, S) do { \
    S##0 = *(const f32x4*)(apA + (T) * 32); \
    S##1 = *(const f32x4*)(apA + (T) * 32 + 4); \
    S##2 = *(const f32x4*)(apA + (T) * 32 + 8); \
    S##3 = *(const f32x4*)(apA + (T) * 32 + 12); } while (0)
#define CVT_WRITE(S, CUR) do { \
    u32x4 _w0, _w1; \
    _w0[0] = cvtpk(S##0[0], S##0[1]); _w0[1] = cvtpk(S##0[2], S##0[3]); \
    _w0[2] = cvtpk(S##1[0], S##1[1]); _w0[3] = cvtpk(S##1[2], S##1[3]); \
    _w1[0] = cvtpk(S##2[0], S##2[1]); _w1[1] = cvtpk(S##2[2], S##2[3]); \
    _w1[2] = cvtpk(S##3[0], S##3[1]); _w1[3] = cvtpk(S##3[2], S##3[3]); \
    *(u32x4*)(As + (CUR) * 4096 + aw0) = _w0; \
    *(u32x4*)(As + (CUR) * 4096 + aw1) = _w1; } while (0)
#define MFMA_STEP(CUR) do { \
    s16x8 fa[4], fb[4]; \
    _Pragma("unroll") for (int i = 0; i < 4; ++i) \
      fa[i] = *(const s16x8*)(As + (CUR) * 4096 + (wm * 64 + i * 16 + fl) * 32 + fro); \
    _Pragma("unroll") for (int j = 0; j < 4; ++j) \
      fb[j] = *(const s16x8*)(Bs + (CUR) * 4096 + (wn * 64 + j * 16 + fl) * 32 + fro); \
    _Pragma("unroll") for (int i = 0; i < 4; ++i) \
      _Pragma("unroll") for (int j = 0; j < 4; ++j) \
        acc[i][j] = __builtin_amdgcn_mfma_f32_16x16x32_bf16(fa[i], fb[j], acc[i][j], 0, 0, 0); \
    } while (0)

  if constexpr (AFP32) {
    // prologue: tile0 -> buf0; A(1) regs in flight
    ISSUE_P(0, qa);
    ISSUE_B(0, 0);
    CVT_WRITE(qa, 0);          // implicit wait on qa only
    ISSUE_P(1, qb);
    WAITVM(4); LGKM0; BARRIER; SBAR;   // drains B(0); P(1) stays in flight
#pragma unroll 1
    for (int t = 0; t < 30; t += 2) {
      // step t (even): compute buf0, stage tile t+1 -> buf1
      ISSUE_B(t + 1, 1);
      CVT_WRITE(qb, 1);        // A(t+1); qb landed during previous step
      ISSUE_P(t + 2, qa);
      MFMA_STEP(0);
      WAITVM(4); LGKM0; BARRIER; SBAR;
      // step t+1 (odd): compute buf1, stage tile t+2 -> buf0
      ISSUE_B(t + 2, 0);
      CVT_WRITE(qa, 0);
      ISSUE_P(t + 3, qb);
      MFMA_STEP(1);
      WAITVM(4); LGKM0; BARRIER; SBAR;
    }
    // step 30: compute buf0, stage tile 31 -> buf1 (no more reg prefetch)
    ISSUE_B(31, 1);
    CVT_WRITE(qb, 1);          // A(31)
    MFMA_STEP(0);
    WAITVM(0); LGKM0; BARRIER; SBAR;
    // step 31
    MFMA_STEP(1);
  } else {
    ISSUE_A16(0, 0); ISSUE_B(0, 0);
    WAITVM(0); BARRIER; SBAR;
#pragma unroll 1
    for (int t = 0; t < 31; ++t) {
      ISSUE_A16(t + 1, (t + 1) & 1);
      ISSUE_B(t + 1, (t + 1) & 1);
      MFMA_STEP(t & 1);
      WAITVM(0); BARRIER; SBAR;
    }
    MFMA_STEP(1);
  }
#undef ISSUE_B
#undef ISSUE_A16
#undef ISSUE_P
#undef CVT_WRITE
#undef MFMA_STEP

  // ---- epilogues: rows m0 + wm*64 + i*16 + fh*4 + r, cols n0 + wn*64 + j*16 + fl
  if constexpr (EPI == 0) {
    ushort* C = (ushort*)Cv;
#pragma unroll
    for (int j = 0; j < 4; ++j) {
      int col = n0 + wn * 64 + j * 16 + fl;
#pragma unroll
      for (int i = 0; i < 4; ++i)
#pragma unroll
        for (int r = 0; r < 4; ++r) {
          int row = m0 + wm * 64 + i * 16 + fh * 4 + r;
          C[(long)row * N + col] = f2bf(acc[i][j][r]);
        }
    }
  } else if constexpr (EPI == 1) {
    ushort* C = (ushort*)Cv;
    float bcol[4];
#pragma unroll
    for (int j = 0; j < 4; ++j) bcol[j] = bias[n0 + wn * 64 + j * 16 + fl];
#pragma unroll
    for (int i = 0; i < 4; ++i)
#pragma unroll
      for (int r = 0; r < 4; ++r) {
        float v[4];
#pragma unroll
        for (int j = 0; j < 4; ++j) v[j] = acc[i][j][r] + bcol[j];
        float m = fmaxf(fmaxf(v[0], v[1]), fmaxf(v[2], v[3]));
#pragma unroll
        for (int o = 1; o <= 8; o <<= 1) m = fmaxf(m, __shfl_xor(m, o));
        float e[4], s = 0.f;
#pragma unroll
        for (int j = 0; j < 4; ++j) { e[j] = __expf(v[j] - m); s += e[j]; }
#pragma unroll
        for (int o = 1; o <= 8; o <<= 1) s += __shfl_xor(s, o);
        float sc = 0.125f / s;
        int row = m0 + wm * 64 + i * 16 + fh * 4 + r;
#pragma unroll
        for (int j = 0; j < 4; ++j)
          C[(long)row * N + n0 + wn * 64 + j * 16 + fl] = f2bf(e[j] * sc);
      }
  } else if constexpr (EPI == 2) {
    ushort* C = (ushort*)Cv;
    float csum[4] = {};
#pragma unroll
    for (int j = 0; j < 4; ++j) {
      int col = n0 + wn * 64 + j * 16 + fl;
#pragma unroll
      for (int i = 0; i < 4; ++i)
#pragma unroll
        for (int r = 0; r < 4; ++r) {
          int row = m0 + wm * 64 + i * 16 + fh * 4 + r;
          float e = __expf(acc[i][j][r]);
          csum[j] += e;
          C[(long)row * N + col] = f2bf(e);
        }
    }
#pragma unroll
    for (int j = 0; j < 4; ++j) {
#pragma unroll
      for (int o = 16; o <= 32; o <<= 1) csum[j] += __shfl_xor(csum[j], o);
    }
    if (fh == 0) {
      int b = m0 >> 12;
      int chunk = ((m0 & 4095) >> 7) * 2 + wm;  // 64 chunks of 64 rows per batch
#pragma unroll
      for (int j = 0; j < 4; ++j)
        kpart[(long)b * 65536 + (long)chunk * 1024 + n0 + wn * 64 + j * 16 + fl] = csum[j];
    }
  } else {
    float* C = (float*)Cv;
#pragma unroll
    for (int j = 0; j < 4; ++j) {
      int col = n0 + wn * 64 + j * 16 + fl;
      float bv = bias[col];
#pragma unroll
      for (int i = 0; i < 4; ++i)
#pragma unroll
        for (int r = 0; r < 4; ++r) {
          int row = m0 + wm * 64 + i * 16 + fh * 4 + r;
          C[(long)row * N + col] = acc[i][j][r] + bv;
        }
    }
  }
}

// ---------------- named GEMM kernels ----------------
__global__ __launch_bounds__(256, 2) void gemm_q(const float* __restrict__ A,
                                                 const ushort* __restrict__ Bm,
                                                 ushort* __restrict__ C,
                                                 const float* __restrict__ bias) {
  gemm_body<1, true>(A, Bm, C, bias, nullptr, blockIdx.x * 128, blockIdx.y * 128);
}
__global__ __launch_bounds__(256, 2) void gemm_k(const float* __restrict__ A,
                                                 const ushort* __restrict__ Bm,
                                                 ushort* __restrict__ C,
                                                 float* __restrict__ kpart) {
  gemm_body<2, true>(A, Bm, C, nullptr, kpart, blockIdx.x * 128, blockIdx.y * 128);
}
__global__ __launch_bounds__(256, 2) void gemm_v(const float* __restrict__ A,
                                                 const ushort* __restrict__ Bm,
                                                 ushort* __restrict__ C) {
  gemm_body<0, true>(A, Bm, C, nullptr, nullptr, blockIdx.x * 128, blockIdx.y * 128);
}
__global__ __launch_bounds__(256, 2) void gemm_o(const ushort* __restrict__ A,
                                                 const ushort* __restrict__ Bm,
                                                 float* __restrict__ C,
                                                 const float* __restrict__ bias) {
  const int z = blockIdx.z;
  gemm_body<3, false>(A + (long)z * 4096 * 1024, Bm + (long)z * 1024 * 1024,
                      C + (long)z * 4096 * 1024, bias, nullptr,
                      blockIdx.x * 128, blockIdx.y * 128);
}

// ---------------- colinv[b][d] = 1 / sum_c kpart[b][c][d] ----------------
__global__ void ksm2_kernel(const float* __restrict__ kpart, float* __restrict__ colinv) {
  int idx = blockIdx.x * 256 + threadIdx.x;  // b*1024+d
  int b = idx >> 10, d = idx & 1023;
  float s = 0.f;
  for (int c = 0; c < 64; ++c) s += kpart[(long)b * 65536 + (long)c * 1024 + d];
  colinv[idx] = 1.0f / s;
}

// ---------------- ctx partial: part[chunk][bh][dk][e] = sum_{n in chunk(512)} expk[n,dk]*v[n,e] ----------------
__global__ __launch_bounds__(256, 2) void ctx_partial_kernel(
    const ushort* __restrict__ Ksm, const ushort* __restrict__ Vp, float* __restrict__ part) {
  __shared__ ushort Ks[128 * 64];
  __shared__ ushort Vs[128 * 64];
  const int chunk = blockIdx.x;  // 8 chunks of 512 rows
  const int bh = blockIdx.y;     // 64
  const int b = bh >> 4, h = bh & 15;
  const int tid = threadIdx.x, wave = tid >> 6, lane = tid & 63;
  const int fl = lane & 15, fh = lane >> 4;
  f32x4 acc[4] = {};
  for (int t = 0; t < 4; ++t) {
    const long base = ((long)(b * N_ + chunk * 512 + t * 128)) * D_ + h * 64;
    __syncthreads();
#pragma unroll
    for (int i = 0; i < 4; ++i) {
      int c = i * 256 + tid;
      int r = c >> 3, k8 = (c & 7) * 8;
      ushort* lk = Ks + (long)(i * 256 + wave * 64) * 8;
      ushort* lv = Vs + (long)(i * 256 + wave * 64) * 8;
      gld16(Ksm + base + (long)r * D_ + k8, lk);
      gld16(Vp + base + (long)r * D_ + k8, lv);
    }
    __syncthreads();
#pragma unroll
    for (int s = 0; s < 4; ++s) {
      s16x8 fa;
#pragma unroll
      for (int j = 0; j < 8; ++j)
        fa[j] = (short)Ks[(s * 32 + fh * 8 + j) * 64 + wave * 16 + fl];
#pragma unroll
      for (int jt = 0; jt < 4; ++jt) {
        s16x8 fb;
#pragma unroll
        for (int j = 0; j < 8; ++j)
          fb[j] = (short)Vs[(s * 32 + fh * 8 + j) * 64 + jt * 16 + fl];
        acc[jt] = __builtin_amdgcn_mfma_f32_16x16x32_bf16(fa, fb, acc[jt], 0, 0, 0);
      }
    }
  }
  float* dst = part + ((long)chunk * 64 + bh) * 4096;
#pragma unroll
  for (int jt = 0; jt < 4; ++jt)
#pragma unroll
    for (int r = 0; r < 4; ++r)
      dst[(wave * 16 + fh * 4 + r) * 64 + jt * 16 + fl] = acc[jt][r];
}

// ctxb[bh][dk][e] = bf16( colinv[b,h*64+dk] * sum_ch part + bv[h*64+e] )
__global__ void ctx_reduce_kernel(const float* __restrict__ part, const float* __restrict__ bv,
                                  const float* __restrict__ colinv, ushort* __restrict__ ctxb) {
  int idx = blockIdx.x * 256 + threadIdx.x;
  int e = idx & 63;
  int dk = (idx >> 6) & 63;
  int h = (idx >> 12) & 15;
  int b = idx >> 16;
  float s = 0.f;
#pragma unroll
  for (int c = 0; c < 8; ++c) s += part[(long)c * 262144 + idx];
  ctxb[idx] = f2bf(s * colinv[b * 1024 + h * 64 + dk] + bv[h * 64 + e]);
}

// Mb[b][o, h*64+dk] = sum_e Wo[o, h*64+e] * ctx[b,h][dk,e]
__global__ __launch_bounds__(256, 2) void mb_kernel(
    const ushort* __restrict__ Wob, const ushort* __restrict__ ctxb, ushort* __restrict__ Mb) {
  const int o0 = blockIdx.x * 64, h = blockIdx.y, b = blockIdx.z;
  const int tid = threadIdx.x, wave = tid >> 6, lane = tid & 63;
  const int fl = lane & 15, fh = lane >> 4;
  const ushort* ctxh = ctxb + ((long)(b * 16 + h)) * 4096;
  f32x4 acc[4] = {};
#pragma unroll
  for (int s = 0; s < 2; ++s) {
    s16x8 fa = *(const s16x8*)(Wob + (long)(o0 + wave * 16 + fl) * D_ + h * 64 + s * 32 + fh * 8);
#pragma unroll
    for (int jt = 0; jt < 4; ++jt) {
      s16x8 fb = *(const s16x8*)(ctxh + (long)(jt * 16 + fl) * 64 + s * 32 + fh * 8);
      acc[jt] = __builtin_amdgcn_mfma_f32_16x16x32_bf16(fa, fb, acc[jt], 0, 0, 0);
    }
  }
  ushort* dst = Mb + (long)b * (D_ * D_);
#pragma unroll
  for (int jt = 0; jt < 4; ++jt)
#pragma unroll
    for (int r = 0; r < 4; ++r)
      dst[(long)(o0 + wave * 16 + fh * 4 + r) * D_ + h * 64 + jt * 16 + fl] = f2bf(acc[jt][r]);
}

// ---------------- launch ----------------
extern "C" void kernel_launch(void* const* d_in, const int* in_sizes, int n_in,
                              void* d_out, int out_size, void* d_ws, size_t ws_size,
                              hipStream_t stream) {
  const float* q_in = (const float*)d_in[0];
  const float* k_in = (const float*)d_in[1];
  const float* v_in = (const float*)d_in[2];
  const float* Wq = (const float*)d_in[3];
  const float* bq = (const float*)d_in[4];
  const float* Wk = (const float*)d_in[5];
  const float* Wv = (const float*)d_in[7];
  const float* bv = (const float*)d_in[8];
  const float* Wo = (const float*)d_in[9];
  const float* bo = (const float*)d_in[10];

  char* ws = (char*)d_ws;
  ushort* Wb = (ushort*)(ws + 0);              // 8 MB
  ushort* Qp = (ushort*)(ws + 8388608);        // 32 MB
  ushort* Kp = (ushort*)(ws + 41943040);       // 32 MB
  ushort* Vp = (ushort*)(ws + 75497472);       // 32 MB
  float* kpart = (float*)(ws + 109051904);     // [4][64][1024] f32 = 1 MB
  float* colinv = (float*)(ws + 110100480);    // 16 KB
  float* ctxpart = (float*)(ws + 110116864);   // [8][64][4096] f32 = 8 MB
  ushort* ctxb = (ushort*)(ws + 118505472);    // 512 KB
  ushort* Mb = (ushort*)(ws + 119029760);      // 8 MB

  ushort* Wbq = Wb;
  ushort* Wbk = Wb + 1048576;
  ushort* Wbv = Wb + 2097152;
  ushort* Wbo = Wb + 3145728;

  conv_w_kernel<<<dim3(128, 1, 4), 256, 0, stream>>>(Wq, Wk, Wv, Wo, Wb);

  // projections: fp32 A read directly; M=16384 (128 m-tiles), N=1024 (8 n-tiles)
  gemm_q<<<dim3(128, 8), 256, 0, stream>>>(q_in, Wbq, Qp, bq);
  gemm_k<<<dim3(128, 8), 256, 0, stream>>>(k_in, Wbk, Kp, kpart);
  gemm_v<<<dim3(128, 8), 256, 0, stream>>>(v_in, Wbv, Vp);

  ksm2_kernel<<<16, 256, 0, stream>>>(kpart, colinv);

  ctx_partial_kernel<<<dim3(8, 64), 256, 0, stream>>>(Kp, Vp, ctxpart);
  ctx_reduce_kernel<<<1024, 256, 0, stream>>>(ctxpart, bv, colinv, ctxb);
  mb_kernel<<<dim3(16, 16, 4), 256, 0, stream>>>(Wbo, ctxb, Mb);

  // final: per-batch out = Qp_b @ Mb_b^T + bo (fp32 out); 32 m-tiles x 8 n-tiles x 4 z
  gemm_o<<<dim3(32, 8, 4), 256, 0, stream>>>(Qp, Mb, (float*)d_out, bo);
}